// Round 13
// baseline (704.140 us; speedup 1.0000x reference)
//
#include <hip/hip_runtime.h>

#define L_T 512
#define BATCH 1024
#define LB (L_T*BATCH)
#define NT (LB/64)

typedef short bf16x8 __attribute__((ext_vector_type(8)));
typedef float f32x4 __attribute__((ext_vector_type(4)));
typedef unsigned short u16;

#define MFMA_B16(a,b,c) __builtin_amdgcn_mfma_f32_16x16x32_bf16((a),(b),(c),0,0,0)

__device__ __forceinline__ short f2bs(float f){
  union{float f; unsigned u;} c; c.f=f;
  unsigned r = (c.u + 0x7FFFu + ((c.u>>16)&1u)) >> 16;
  return (short)r;
}

__device__ __forceinline__ unsigned cvtpk(float lo, float hi){
  unsigned d;
  asm("v_cvt_pk_bf16_f32 %0, %1, %2" : "=v"(d) : "v"(lo), "v"(hi));
  return d;
}

// fast activations (validated R7-R12: absmax unchanged at 0.03125)
__device__ __forceinline__ float fsig(float x){
  return __builtin_amdgcn_rcpf(1.0f + __expf(-x));
}
__device__ __forceinline__ float ftanh(float x){
  return 1.0f - 2.0f*__builtin_amdgcn_rcpf(1.0f + __expf(2.0f*x));
}

__device__ __forceinline__ void store8(u16* d, float4 a, float4 b){
  bf16x8 v;
  v[0]=f2bs(a.x); v[1]=f2bs(a.y); v[2]=f2bs(a.z); v[3]=f2bs(a.w);
  v[4]=f2bs(b.x); v[5]=f2bs(b.y); v[6]=f2bs(b.z); v[7]=f2bs(b.w);
  *(bf16x8*)d = v;
}

__device__ __forceinline__ bf16x8 bfrag_f32(const float* p){
  float4 a = *(const float4*)p;
  float4 b = *(const float4*)(p+4);
  bf16x8 v;
  v[0]=f2bs(a.x); v[1]=f2bs(a.y); v[2]=f2bs(a.z); v[3]=f2bs(a.w);
  v[4]=f2bs(b.x); v[5]=f2bs(b.y); v[6]=f2bs(b.z); v[7]=f2bs(b.w);
  return v;
}

__device__ __forceinline__ void dma16(const void* g, void* l){
  __builtin_amdgcn_global_load_lds(
      (const __attribute__((address_space(1))) void*)g,
      (__attribute__((address_space(3))) void*)l, 16, 0, 0);
}

#define SMEM_U16 39552
// mid carving (u16 offsets)
#define M_DT   0
#define M_W1T  5632
#define M_W2T  11264
#define M_TT   16896
#define M_ZW2T 22528
#define M_ZW1T 28160
#define M_ST   30720
#define M_WMUT 33280
#define M_WLST 36096
#define M_BIAS 38912   // 320 f32
// pre-tile carving (reused after mid loop; starts at 0)
#define PT_IN   0
#define PT_W1   2560
#define PT_W2   5120
#define PT_T1   10752
#define PT_BIAS 16384   // 128 f32 -> ends at 16640 u16

// ---------------------------------------------------------------------------
// pre_tile: one 64-row two-layer preprocess tile using caller smem.
// ---------------------------------------------------------------------------
__device__ void pre_tile(
    u16* smem, size_t row0,
    const float* __restrict__ src, const float* __restrict__ W1,
    const float* __restrict__ b1, const float* __restrict__ W2,
    const float* __restrict__ b2,
    u16* __restrict__ out_b16, int ostride, int ooff,
    float* __restrict__ out_f32)
{
  u16* in_t = smem + PT_IN;
  u16* w1t  = smem + PT_W1;
  u16* w2t  = smem + PT_W2;
  u16* t1t  = smem + PT_T1;
  float* lb1 = (float*)(smem + PT_BIAS);
  float* lb2 = lb1 + 64;

  const int t = threadIdx.x;
  __syncthreads();   // WAR vs whatever used smem before

  {
    int r = t>>2, q = t&3;
    const float* ps = src + (row0 + r)*32 + q*8;
    store8(in_t + r*40 + q*8, *(const float4*)ps, *(const float4*)(ps+4));
    const float* pw = W1 + r*32 + q*8;
    store8(w1t + r*40 + q*8, *(const float4*)pw, *(const float4*)(pw+4));
    const float* pw2 = W2 + r*64 + q*16;
    store8(w2t + r*88 + q*16,     *(const float4*)pw2,     *(const float4*)(pw2+4));
    store8(w2t + r*88 + q*16 + 8, *(const float4*)(pw2+8), *(const float4*)(pw2+12));
    if (t < 64) lb1[t] = b1[t];
    else if (t < 128) lb2[t-64] = b2[t-64];
  }
  __syncthreads();

  const int lane = t & 63, wave = t >> 6;
  const int l15 = lane & 15, l4 = lane >> 4;
  const int rs = wave*16;

  {
    bf16x8 a = *(const bf16x8*)(in_t + (rs + l15)*40 + l4*8);
    #pragma unroll
    for (int ct = 0; ct < 4; ++ct) {
      f32x4 acc = {0.f,0.f,0.f,0.f};
      bf16x8 bw = *(const bf16x8*)(w1t + (ct*16 + l15)*40 + l4*8);
      acc = MFMA_B16(a, bw, acc);
      float bias = lb1[ct*16 + l15];
      #pragma unroll
      for (int i = 0; i < 4; ++i) {
        float v = fmaxf(acc[i] + bias, 0.f);
        t1t[(rs + l4*4 + i)*88 + ct*16 + l15] = (u16)f2bs(v);
      }
    }
  }
  __syncthreads();

  {
    bf16x8 a0 = *(const bf16x8*)(t1t + (rs + l15)*88 + l4*8);
    bf16x8 a1 = *(const bf16x8*)(t1t + (rs + l15)*88 + 32 + l4*8);
    #pragma unroll
    for (int ct = 0; ct < 4; ++ct) {
      f32x4 acc = {0.f,0.f,0.f,0.f};
      bf16x8 b0 = *(const bf16x8*)(w2t + (ct*16 + l15)*88 + l4*8);
      bf16x8 b1v = *(const bf16x8*)(w2t + (ct*16 + l15)*88 + 32 + l4*8);
      acc = MFMA_B16(a0, b0, acc);
      acc = MFMA_B16(a1, b1v, acc);
      float bias = lb2[ct*16 + l15];
      #pragma unroll
      for (int i = 0; i < 4; ++i) {
        float v = fmaxf(acc[i] + bias, 0.f);
        size_t gr = row0 + rs + l4*4 + i;
        int col = ct*16 + l15;
        out_b16[gr*(size_t)ostride + ooff + col] = (u16)f2bs(v);
        if (out_f32) out_f32[gr*64 + col] = v;
      }
    }
  }
}

// K0: small pre-kernel — xemb chunks 0-1 + uemb chunk 0.
__global__ __launch_bounds__(256) void k_pre_small(
    const float* __restrict__ obs,
    const float* __restrict__ pxW1, const float* __restrict__ pxb1,
    const float* __restrict__ pxW2, const float* __restrict__ pxb2,
    u16* __restrict__ xemb16, float* __restrict__ xembf32,
    const float* __restrict__ ext,
    const float* __restrict__ puW1, const float* __restrict__ pub1,
    const float* __restrict__ puW2, const float* __restrict__ pub2,
    u16* __restrict__ gen_in)
{
  __shared__ u16 smem[16640];
  int bid = blockIdx.x;
  if (bid < 2048)
    pre_tile(smem, (size_t)bid*64, obs, pxW1, pxb1, pxW2, pxb2,
             xemb16, 64, 0, xembf32);
  else
    pre_tile(smem, (size_t)(bid-2048)*64, ext, puW1, pub1, puW2, pub2,
             gen_in, 128, 64, nullptr);
}

// ===========================================================================
// Phase kernel: 256 blocks. blocks 0-63 = INF chunk P (P<8), 64-127 = GEN
// chunk P-2 (P>=2), 128-255 = MID chunk P-1 (1<=P<=8) + pre-production of
// xemb chunk P+2 (P<=5) and uemb chunk P+1 (P<=6). Chunk = 64 steps.
// ===========================================================================

// ---------------- INF role ----------------
__device__ void inf_phase(
    int P, u16* smem,
    const u16* __restrict__ xin,              // xemb16 [LB][64]
    const float* __restrict__ Wih, const float* __restrict__ Whh,
    const float* __restrict__ bih, const float* __restrict__ bhh,
    u16* __restrict__ dseq_out,               // mu region u16 view [LB][64]
    float* __restrict__ hstate)               // [1024][64] f32
{
  u16* xchunk = smem;            // 2 * 8192
  u16* ht     = smem + 16384;    // 2 * 1152

  const int t = threadIdx.x;
  const int lane = t & 63, wave = t >> 6;
  const int l15 = lane & 15, l4 = lane >> 4;
  const int b0 = blockIdx.x * 16;
  const int kcol = wave*16 + l15;
  const int c0   = wave*16 + l4*4;

  bf16x8 wihf[3][2], whhf[3][2];
  #pragma unroll
  for (int g = 0; g < 3; ++g) {
    int grow = g*64 + kcol;
    #pragma unroll
    for (int kc = 0; kc < 2; ++kc) {
      wihf[g][kc] = bfrag_f32(Wih + (size_t)grow*64 + kc*32 + l4*8);
      whhf[g][kc] = bfrag_f32(Whh + (size_t)grow*64 + kc*32 + l4*8);
    }
  }
  f32x4 bv0, bv1, bvi, bvh;
  #pragma unroll
  for (int i = 0; i < 4; ++i) {
    bv0[i] = bih[c0+i]      + bhh[c0+i];
    bv1[i] = bih[64+c0+i]   + bhh[64+c0+i];
    bvi[i] = bih[128+c0+i];
    bvh[i] = bhh[128+c0+i];
  }

  auto issue_chunk = [&](int gc, int bufi){
    const size_t step0 = (size_t)gc*8;
    u16* dst0 = xchunk + bufi*8192;
    #pragma unroll
    for (int j = 0; j < 4; ++j) {
      int o = (j*4 + wave)*1024;
      int slot = o/16 + lane;
      int r_all = slot >> 3;
      int q = slot & 7;
      int slice = r_all >> 4, r = r_all & 15;
      int qs = q ^ (r & 7);
      const u16* g = xin + ((step0 + slice)*BATCH + b0 + r)*64 + qs*8;
      dma16(g, dst0 + o/2);
    }
  };

  float h[4];
  if (P == 0) { h[0]=h[1]=h[2]=h[3]=0.f; }
  else {
    float4 hv = *(const float4*)(hstate + (size_t)(b0 + l15)*64 + c0);
    h[0]=hv.x; h[1]=hv.y; h[2]=hv.z; h[3]=hv.w;
  }

  f32x4 gp0, gp1, gp2;
  issue_chunk(P*8, 0);

  for (int cc = 0; cc < 8; ++cc) {
    const int gc = P*8 + cc;
    const int cb = cc & 1;
    const u16* xbuf = xchunk + cb*8192;
    #pragma unroll
    for (int sp = 0; sp < 8; ++sp) {
      const int step = gc*8 + sp;

      {
        uint2 pv; pv.x = cvtpk(h[0], h[1]); pv.y = cvtpk(h[2], h[3]);
        *(uint2*)(ht + (sp&1)*1152 + l15*72 + c0) = pv;
      }

      if (sp == 0) asm volatile("s_waitcnt vmcnt(0)" ::: "memory");
      asm volatile("s_waitcnt lgkmcnt(0)\n\ts_barrier" ::: "memory");

      const u16* htr = ht + (sp&1)*1152 + l15*72;
      bf16x8 ha0 = *(const bf16x8*)(htr + l4*8);
      bf16x8 ha1 = *(const bf16x8*)(htr + 32 + l4*8);

      f32x4 a0, a1, a2;
      if (sp == 0) {
        const u16* xb = xbuf + l15*64;
        bf16x8 xa[2];
        #pragma unroll
        for (int kc = 0; kc < 2; ++kc)
          xa[kc] = *(const bf16x8*)(xb + (((l4 + 4*kc) ^ (l15 & 7)) * 8));
        a0 = bv0; a1 = bv1; a2 = bvi;
        #pragma unroll
        for (int kc = 0; kc < 2; ++kc) {
          a0 = MFMA_B16(wihf[0][kc], xa[kc], a0);
          a1 = MFMA_B16(wihf[1][kc], xa[kc], a1);
          a2 = MFMA_B16(wihf[2][kc], xa[kc], a2);
        }
      } else {
        a0 = gp0; a1 = gp1; a2 = gp2;
      }

      if (sp == 1 && cc + 1 < 8) issue_chunk(gc + 1, cb ^ 1);

      f32x4 g0 = MFMA_B16(whhf[0][0], ha0, a0);
      g0       = MFMA_B16(whhf[0][1], ha1, g0);
      f32x4 g1 = MFMA_B16(whhf[1][0], ha0, a1);
      g1       = MFMA_B16(whhf[1][1], ha1, g1);
      f32x4 gn = MFMA_B16(whhf[2][0], ha0, bvh);
      gn       = MFMA_B16(whhf[2][1], ha1, gn);

      if (sp < 7) {
        const u16* xb = xbuf + (sp+1)*1024 + l15*64;
        bf16x8 xn[2];
        #pragma unroll
        for (int kc = 0; kc < 2; ++kc)
          xn[kc] = *(const bf16x8*)(xb + (((l4 + 4*kc) ^ (l15 & 7)) * 8));
        gp0 = bv0; gp1 = bv1; gp2 = bvi;
        #pragma unroll
        for (int kc = 0; kc < 2; ++kc) {
          gp0 = MFMA_B16(wihf[0][kc], xn[kc], gp0);
          gp1 = MFMA_B16(wihf[1][kc], xn[kc], gp1);
          gp2 = MFMA_B16(wihf[2][kc], xn[kc], gp2);
        }
      }

      #pragma unroll
      for (int i = 0; i < 4; ++i) {
        float r = fsig(g0[i]);
        float z = fsig(g1[i]);
        float n = ftanh(a2[i] + r*gn[i]);
        h[i] = z*(h[i] - n) + n;
      }

      {
        uint2 dv; dv.x = cvtpk(h[0], h[1]); dv.y = cvtpk(h[2], h[3]);
        *(uint2*)(dseq_out + ((size_t)step*BATCH + b0 + l15)*64 + c0) = dv;
      }
    }
  }

  float4 hv; hv.x=h[0]; hv.y=h[1]; hv.z=h[2]; hv.w=h[3];
  *(float4*)(hstate + (size_t)(b0 + l15)*64 + c0) = hv;
}

// ---------------- GEN role ----------------
__device__ void gen_phase(
    int P, u16* smem,
    const u16* __restrict__ xin,              // gen_in [LB][128]
    const float* __restrict__ Wih, const float* __restrict__ Whh,
    const float* __restrict__ bih, const float* __restrict__ bhh,
    float* __restrict__ hseq,
    float* __restrict__ hstate)               // hn region [1024][64] f32
{
  u16* xchunk = smem;            // 2 * 16384
  u16* ht     = smem + 32768;    // 2 * 1152

  const int t = threadIdx.x;
  const int lane = t & 63, wave = t >> 6;
  const int l15 = lane & 15, l4 = lane >> 4;
  const int b0 = (blockIdx.x - 64) * 16;
  const int kcol = wave*16 + l15;
  const int c0   = wave*16 + l4*4;

  bf16x8 wihf[3][4], whhf[3][2];
  #pragma unroll
  for (int g = 0; g < 3; ++g) {
    int grow = g*64 + kcol;
    #pragma unroll
    for (int kc = 0; kc < 4; ++kc)
      wihf[g][kc] = bfrag_f32(Wih + (size_t)grow*128 + kc*32 + l4*8);
    #pragma unroll
    for (int kc = 0; kc < 2; ++kc)
      whhf[g][kc] = bfrag_f32(Whh + (size_t)grow*64 + kc*32 + l4*8);
  }
  f32x4 bv0, bv1, bvi, bvh;
  #pragma unroll
  for (int i = 0; i < 4; ++i) {
    bv0[i] = bih[c0+i]      + bhh[c0+i];
    bv1[i] = bih[64+c0+i]   + bhh[64+c0+i];
    bvi[i] = bih[128+c0+i];
    bvh[i] = bhh[128+c0+i];
  }

  auto issue_chunk = [&](int gc, int bufi){
    const size_t step0 = (size_t)gc*8;
    u16* dst0 = xchunk + bufi*16384;
    #pragma unroll
    for (int j = 0; j < 8; ++j) {
      int o = (j*4 + wave)*1024;
      int slot = o/16 + lane;
      int r_all = slot >> 4;
      int q = slot & 15;
      int slice = r_all >> 4, r = r_all & 15;
      int qs = q ^ (r & 7);
      const u16* g = xin + ((step0 + slice)*BATCH + b0 + r)*128 + qs*8;
      dma16(g, dst0 + o/2);
    }
  };

  float h[4];
  if (P == 2) { h[0]=h[1]=h[2]=h[3]=0.f; }
  else {
    float4 hv = *(const float4*)(hstate + (size_t)(b0 + l15)*64 + c0);
    h[0]=hv.x; h[1]=hv.y; h[2]=hv.z; h[3]=hv.w;
  }

  const int C0 = (P - 2) * 8;
  f32x4 gp0, gp1, gp2;
  issue_chunk(C0, 0);

  for (int cc = 0; cc < 8; ++cc) {
    const int gc = C0 + cc;
    const int cb = cc & 1;
    const u16* xbuf = xchunk + cb*16384;
    #pragma unroll
    for (int sp = 0; sp < 8; ++sp) {
      const int step = gc*8 + sp;

      {
        uint2 pv; pv.x = cvtpk(h[0], h[1]); pv.y = cvtpk(h[2], h[3]);
        *(uint2*)(ht + (sp&1)*1152 + l15*72 + c0) = pv;
        float4 hv; hv.x=h[0]; hv.y=h[1]; hv.z=h[2]; hv.w=h[3];
        *(float4*)(hseq + ((size_t)step*BATCH + b0 + l15)*64 + c0) = hv;
      }

      if (sp == 0) asm volatile("s_waitcnt vmcnt(0)" ::: "memory");
      asm volatile("s_waitcnt lgkmcnt(0)\n\ts_barrier" ::: "memory");

      const u16* htr = ht + (sp&1)*1152 + l15*72;
      bf16x8 ha0 = *(const bf16x8*)(htr + l4*8);
      bf16x8 ha1 = *(const bf16x8*)(htr + 32 + l4*8);

      f32x4 a0, a1, a2;
      if (sp == 0) {
        const u16* xb = xbuf + l15*128;
        bf16x8 xa[4];
        #pragma unroll
        for (int kc = 0; kc < 4; ++kc)
          xa[kc] = *(const bf16x8*)(xb + (((l4 + 4*kc) ^ (l15 & 7)) * 8));
        a0 = bv0; a1 = bv1; a2 = bvi;
        #pragma unroll
        for (int kc = 0; kc < 4; ++kc) {
          a0 = MFMA_B16(wihf[0][kc], xa[kc], a0);
          a1 = MFMA_B16(wihf[1][kc], xa[kc], a1);
          a2 = MFMA_B16(wihf[2][kc], xa[kc], a2);
        }
      } else {
        a0 = gp0; a1 = gp1; a2 = gp2;
      }

      if (sp == 1 && cc + 1 < 8) issue_chunk(gc + 1, cb ^ 1);

      f32x4 g0 = MFMA_B16(whhf[0][0], ha0, a0);
      g0       = MFMA_B16(whhf[0][1], ha1, g0);
      f32x4 g1 = MFMA_B16(whhf[1][0], ha0, a1);
      g1       = MFMA_B16(whhf[1][1], ha1, g1);
      f32x4 gn = MFMA_B16(whhf[2][0], ha0, bvh);
      gn       = MFMA_B16(whhf[2][1], ha1, gn);

      if (sp < 7) {
        const u16* xb = xbuf + (sp+1)*2048 + l15*128;
        bf16x8 xn[4];
        #pragma unroll
        for (int kc = 0; kc < 4; ++kc)
          xn[kc] = *(const bf16x8*)(xb + (((l4 + 4*kc) ^ (l15 & 7)) * 8));
        gp0 = bv0; gp1 = bv1; gp2 = bvi;
        #pragma unroll
        for (int kc = 0; kc < 4; ++kc) {
          gp0 = MFMA_B16(wihf[0][kc], xn[kc], gp0);
          gp1 = MFMA_B16(wihf[1][kc], xn[kc], gp1);
          gp2 = MFMA_B16(wihf[2][kc], xn[kc], gp2);
        }
      }

      #pragma unroll
      for (int i = 0; i < 4; ++i) {
        float r = fsig(g0[i]);
        float z = fsig(g1[i]);
        float n = ftanh(a2[i] + r*gn[i]);
        h[i] = z*(h[i] - n) + n;
      }
    }
  }

  float4 hv; hv.x=h[0]; hv.y=h[1]; hv.z=h[2]; hv.w=h[3];
  *(float4*)(hstate + (size_t)(b0 + l15)*64 + c0) = hv;
}

// ---------------- MID role (posterior+sample+z_emb + pre-production) -------
__device__ void mid_phase(
    int P, u16* smem,
    const u16* __restrict__ dseq,
    const float* __restrict__ eps,
    const float* __restrict__ W1, const float* __restrict__ b1,
    const float* __restrict__ W2, const float* __restrict__ b2,
    const float* __restrict__ Wmu, const float* __restrict__ bmu,
    const float* __restrict__ Wls, const float* __restrict__ bls,
    const float* __restrict__ zW1, const float* __restrict__ zb1,
    const float* __restrict__ zW2, const float* __restrict__ zb2,
    float* __restrict__ out_mu, float* __restrict__ out_ls, float* __restrict__ out_s,
    u16* __restrict__ gen_in,
    // pre-production inputs
    const float* __restrict__ obs,
    const float* __restrict__ pxW1, const float* __restrict__ pxb1,
    const float* __restrict__ pxW2, const float* __restrict__ pxb2,
    u16* __restrict__ xemb16, float* __restrict__ xembf32,
    const float* __restrict__ ext,
    const float* __restrict__ puW1, const float* __restrict__ pub1,
    const float* __restrict__ puW2, const float* __restrict__ pub2)
{
  const int t = threadIdx.x;
  const int bidm = blockIdx.x - 128;          // 0..127

  if (P >= 1 && P <= 8) {
    u16* dt   = smem + M_DT;
    u16* w1t  = smem + M_W1T;
    u16* w2t  = smem + M_W2T;
    u16* tt   = smem + M_TT;
    u16* zw2t = smem + M_ZW2T;
    u16* zw1t = smem + M_ZW1T;
    u16* st   = smem + M_ST;
    u16* wmut = smem + M_WMUT;
    u16* wlst = smem + M_WLST;
    float* fb = (float*)(smem + M_BIAS);
    float* lb1 = fb, *lb2 = fb+64, *lbz1 = fb+128, *lbz2 = fb+192;
    float* lbmu = fb+256, *lbls = fb+288;

    {
      int r = t>>2, q = t&3;
      const float* p1 = W1 + r*64 + q*16;
      store8(w1t + r*88 + q*16,     *(const float4*)p1,     *(const float4*)(p1+4));
      store8(w1t + r*88 + q*16 + 8, *(const float4*)(p1+8), *(const float4*)(p1+12));
      const float* p2 = W2 + r*64 + q*16;
      store8(w2t + r*88 + q*16,     *(const float4*)p2,     *(const float4*)(p2+4));
      store8(w2t + r*88 + q*16 + 8, *(const float4*)(p2+8), *(const float4*)(p2+12));
      const float* pz2 = zW2 + r*64 + q*16;
      store8(zw2t + r*88 + q*16,     *(const float4*)pz2,     *(const float4*)(pz2+4));
      store8(zw2t + r*88 + q*16 + 8, *(const float4*)(pz2+8), *(const float4*)(pz2+12));
      const float* pz1 = zW1 + r*32 + q*8;
      store8(zw1t + r*40 + q*8, *(const float4*)pz1, *(const float4*)(pz1+4));
      if (t < 128) {
        int r2 = t>>2, q2 = t&3;
        const float* pm = Wmu + r2*64 + q2*16;
        store8(wmut + r2*88 + q2*16,     *(const float4*)pm,     *(const float4*)(pm+4));
        store8(wmut + r2*88 + q2*16 + 8, *(const float4*)(pm+8), *(const float4*)(pm+12));
      } else {
        int t2 = t - 128; int r2 = t2>>2, q2 = t2&3;
        const float* pl = Wls + r2*64 + q2*16;
        store8(wlst + r2*88 + q2*16,     *(const float4*)pl,     *(const float4*)(pl+4));
        store8(wlst + r2*88 + q2*16 + 8, *(const float4*)(pl+8), *(const float4*)(pl+12));
      }
      if (t < 64) { lb1[t] = b1[t]; lbz1[t] = zb1[t]; }
      else if (t < 128) { lb2[t-64] = b2[t-64]; lbz2[t-64] = zb2[t-64]; }
      else if (t < 160) lbmu[t-128] = bmu[t-128];
      else if (t < 192) lbls[t-160] = bls[t-160];
    }

    const int lane = t & 63, wave = t >> 6;
    const int l15 = lane & 15, l4 = lane >> 4;
    const int rs = wave*16;
    const size_t t0 = (size_t)(P - 1) * 64;

    for (int j = 0; j < 8; ++j) {
      const size_t row0 = t0*BATCH + ((size_t)bidm*8 + j)*64;

      __syncthreads();
      {
        int r = t>>2, q = t&3;
        const u16* pd = dseq + (row0 + r)*64 + q*16;
        *(bf16x8*)(dt + r*88 + q*16)     = *(const bf16x8*)pd;
        *(bf16x8*)(dt + r*88 + q*16 + 8) = *(const bf16x8*)(pd + 8);
      }
      __syncthreads();

      {
        bf16x8 a0 = *(const bf16x8*)(dt + (rs + l15)*88 + l4*8);
        bf16x8 a1 = *(const bf16x8*)(dt + (rs + l15)*88 + 32 + l4*8);
        #pragma unroll
        for (int ct = 0; ct < 4; ++ct) {
          f32x4 c1 = {0.f,0.f,0.f,0.f}, c2 = {0.f,0.f,0.f,0.f};
          bf16x8 w1a = *(const bf16x8*)(w1t + (ct*16 + l15)*88 + l4*8);
          bf16x8 w1b = *(const bf16x8*)(w1t + (ct*16 + l15)*88 + 32 + l4*8);
          bf16x8 w2a = *(const bf16x8*)(w2t + (ct*16 + l15)*88 + l4*8);
          bf16x8 w2b = *(const bf16x8*)(w2t + (ct*16 + l15)*88 + 32 + l4*8);
          c1 = MFMA_B16(a0, w1a, c1); c1 = MFMA_B16(a1, w1b, c1);
          c2 = MFMA_B16(a0, w2a, c2); c2 = MFMA_B16(a1, w2b, c2);
          float bb1 = lb1[ct*16 + l15], bb2 = lb2[ct*16 + l15];
          #pragma unroll
          for (int i = 0; i < 4; ++i) {
            float tv = fmaxf(c1[i] + bb1, 0.f) * fsig(c2[i] + bb2);
            tt[(rs + l4*4 + i)*88 + ct*16 + l15] = (u16)f2bs(tv);
          }
        }
      }
      __syncthreads();

      {
        bf16x8 a0 = *(const bf16x8*)(tt + (rs + l15)*88 + l4*8);
        bf16x8 a1 = *(const bf16x8*)(tt + (rs + l15)*88 + 32 + l4*8);
        #pragma unroll
        for (int ct = 0; ct < 2; ++ct) {
          f32x4 cmu = {0.f,0.f,0.f,0.f}, cls = {0.f,0.f,0.f,0.f};
          bf16x8 wma = *(const bf16x8*)(wmut + (ct*16 + l15)*88 + l4*8);
          bf16x8 wmb = *(const bf16x8*)(wmut + (ct*16 + l15)*88 + 32 + l4*8);
          bf16x8 wla = *(const bf16x8*)(wlst + (ct*16 + l15)*88 + l4*8);
          bf16x8 wlb = *(const bf16x8*)(wlst + (ct*16 + l15)*88 + 32 + l4*8);
          cmu = MFMA_B16(a0, wma, cmu); cmu = MFMA_B16(a1, wmb, cmu);
          cls = MFMA_B16(a0, wla, cls); cls = MFMA_B16(a1, wlb, cls);
          float bm = lbmu[ct*16 + l15], bl = lbls[ct*16 + l15];
          #pragma unroll
          for (int i = 0; i < 4; ++i) {
            size_t R = row0 + rs + l4*4 + i;
            int col = ct*16 + l15;
            float mu = cmu[i] + bm;
            float ls = cls[i] + bl;
            float e  = eps[R*32 + col];
            float s  = mu + __expf(0.5f*ls)*e;
            out_mu[R*32 + col] = mu;
            out_ls[R*32 + col] = ls;
            out_s [R*32 + col] = s;
            st[(rs + l4*4 + i)*40 + col] = (u16)f2bs(s);
          }
        }
      }
      __syncthreads();

      {
        bf16x8 a = *(const bf16x8*)(st + (rs + l15)*40 + l4*8);
        #pragma unroll
        for (int ct = 0; ct < 4; ++ct) {
          f32x4 acc = {0.f,0.f,0.f,0.f};
          bf16x8 bw = *(const bf16x8*)(zw1t + (ct*16 + l15)*40 + l4*8);
          acc = MFMA_B16(a, bw, acc);
          float bias = lbz1[ct*16 + l15];
          #pragma unroll
          for (int i = 0; i < 4; ++i) {
            float v = fmaxf(acc[i] + bias, 0.f);
            dt[(rs + l4*4 + i)*88 + ct*16 + l15] = (u16)f2bs(v);
          }
        }
      }
      __syncthreads();

      {
        bf16x8 a0 = *(const bf16x8*)(dt + (rs + l15)*88 + l4*8);
        bf16x8 a1 = *(const bf16x8*)(dt + (rs + l15)*88 + 32 + l4*8);
        #pragma unroll
        for (int ct = 0; ct < 4; ++ct) {
          f32x4 acc = {0.f,0.f,0.f,0.f};
          bf16x8 b0 = *(const bf16x8*)(zw2t + (ct*16 + l15)*88 + l4*8);
          bf16x8 b1v = *(const bf16x8*)(zw2t + (ct*16 + l15)*88 + 32 + l4*8);
          acc = MFMA_B16(a0, b0, acc);
          acc = MFMA_B16(a1, b1v, acc);
          float bias = lbz2[ct*16 + l15];
          #pragma unroll
          for (int i = 0; i < 4; ++i) {
            float v = fmaxf(acc[i] + bias, 0.f);
            size_t gr = row0 + rs + l4*4 + i;
            gen_in[gr*128 + ct*16 + l15] = (u16)f2bs(v);
          }
        }
      }
    }
  }

  // ---- pre-production on slack: xemb chunk P+2, uemb chunk P+1 ----
  if (P <= 5) {
    for (int k = 0; k < 8; ++k) {
      size_t tile = (size_t)(P+2)*1024 + (size_t)bidm*8 + k;
      pre_tile(smem, tile*64, obs, pxW1, pxb1, pxW2, pxb2,
               xemb16, 64, 0, xembf32);
    }
  }
  if (P <= 6) {
    for (int k = 0; k < 8; ++k) {
      size_t tile = (size_t)(P+1)*1024 + (size_t)bidm*8 + k;
      pre_tile(smem, tile*64, ext, puW1, pub1, puW2, pub2,
               gen_in, 128, 64, nullptr);
    }
  }
}

// ---------------- dispatcher ----------------
__global__ __launch_bounds__(256, 1) void k_phase(
    int P,
    const u16* xemb16_c, u16* gen_in,
    const float* eps,
    const float* iWih, const float* iWhh, const float* ibih, const float* ibhh,
    const float* gWih, const float* gWhh, const float* gbih, const float* gbhh,
    const float* poW1, const float* pob1, const float* poW2, const float* pob2,
    const float* poWmu, const float* pobmu, const float* poWls, const float* pobls,
    const float* pzW1, const float* pzb1, const float* pzW2, const float* pzb2,
    u16* dseq, float* out_mu, float* out_ls, float* out_s,
    float* hseq, float* hn, float* hstate_inf,
    const float* obs,
    const float* pxW1, const float* pxb1, const float* pxW2, const float* pxb2,
    u16* xemb16_w, float* xembf32,
    const float* ext,
    const float* puW1, const float* pub1, const float* puW2, const float* pub2)
{
  __shared__ u16 smem[SMEM_U16];
  const int bid = blockIdx.x;
  if (bid < 64) {
    if (P < 8)
      inf_phase(P, smem, xemb16_c, iWih, iWhh, ibih, ibhh, dseq, hstate_inf);
  } else if (bid < 128) {
    if (P >= 2)
      gen_phase(P, smem, gen_in, gWih, gWhh, gbih, gbhh, hseq, hn);
  } else {
    mid_phase(P, smem, dseq, eps, poW1, pob1, poW2, pob2,
              poWmu, pobmu, poWls, pobls, pzW1, pzb1, pzW2, pzb2,
              out_mu, out_ls, out_s, gen_in,
              obs, pxW1, pxb1, pxW2, pxb2, xemb16_w, xembf32,
              ext, puW1, pub1, puW2, pub2);
  }
}

// ---------------------------------------------------------------------------

extern "C" void kernel_launch(void* const* d_in, const int* in_sizes, int n_in,
                              void* d_out, int out_size, void* d_ws, size_t ws_size,
                              hipStream_t stream) {
  const float* ext  = (const float*)d_in[0];
  const float* obs  = (const float*)d_in[1];
  const float* eps  = (const float*)d_in[2];
  const float* puW1 = (const float*)d_in[3];  const float* pub1 = (const float*)d_in[4];
  const float* puW2 = (const float*)d_in[5];  const float* pub2 = (const float*)d_in[6];
  const float* pxW1 = (const float*)d_in[7];  const float* pxb1 = (const float*)d_in[8];
  const float* pxW2 = (const float*)d_in[9];  const float* pxb2 = (const float*)d_in[10];
  const float* pzW1 = (const float*)d_in[11]; const float* pzb1 = (const float*)d_in[12];
  const float* pzW2 = (const float*)d_in[13]; const float* pzb2 = (const float*)d_in[14];
  const float* poW1 = (const float*)d_in[15]; const float* pob1 = (const float*)d_in[16];
  const float* poW2 = (const float*)d_in[17]; const float* pob2 = (const float*)d_in[18];
  const float* poWmu= (const float*)d_in[19]; const float* pobmu= (const float*)d_in[20];
  const float* poWls= (const float*)d_in[21]; const float* pobls= (const float*)d_in[22];
  const float* iWih = (const float*)d_in[23]; const float* iWhh = (const float*)d_in[24];
  const float* ibih = (const float*)d_in[25]; const float* ibhh = (const float*)d_in[26];
  const float* gWih = (const float*)d_in[27]; const float* gWhh = (const float*)d_in[28];
  const float* gbih = (const float*)d_in[29]; const float* gbhh = (const float*)d_in[30];

  float* out = (float*)d_out;
  const size_t OFF_MU   = 0;
  const size_t OFF_LS   = (size_t)LB*32;
  const size_t OFF_S    = (size_t)LB*64;
  const size_t OFF_HSEQ = (size_t)LB*96;
  const size_t OFF_XEMB = (size_t)LB*96 + (size_t)LB*64;
  const size_t OFF_HN   = OFF_XEMB + (size_t)LB*64;

  u16* gen_in = (u16*)d_ws;                              // [LB][128] bf16 (z|u)
  u16* dseq   = (u16*)(out + OFF_MU);                    // [LB][64] bf16 park (mu region)
  u16* xemb16 = (u16*)(out + OFF_HSEQ + (size_t)LB*32);  // [LB][64] bf16 park (hseq 2nd half)
  float* hstate_inf = out + OFF_S + (size_t)LB*32 - 65536;  // s-region tail

  // 1. pre-kernel: xemb chunks 0-1 + uemb chunk 0
  k_pre_small<<<3072, 256, 0, stream>>>(obs, pxW1, pxb1, pxW2, pxb2,
                                        xemb16, out + OFF_XEMB,
                                        ext, puW1, pub1, puW2, pub2, gen_in);
  // 2. pipelined phases: inf chunk P || mid chunk P-1 (+pre-prod) || gen chunk P-2
  for (int P = 0; P < 10; ++P) {
    k_phase<<<256, 256, 0, stream>>>(P, xemb16, gen_in, eps,
                                     iWih, iWhh, ibih, ibhh,
                                     gWih, gWhh, gbih, gbhh,
                                     poW1, pob1, poW2, pob2,
                                     poWmu, pobmu, poWls, pobls,
                                     pzW1, pzb1, pzW2, pzb2,
                                     dseq, out + OFF_MU, out + OFF_LS, out + OFF_S,
                                     out + OFF_HSEQ, out + OFF_HN, hstate_inf,
                                     obs, pxW1, pxb1, pxW2, pxb2,
                                     xemb16, out + OFF_XEMB,
                                     ext, puW1, pub1, puW2, pub2);
  }
}

// Round 14
// 484.598 us; speedup vs baseline: 1.4530x; 1.4530x over previous
//
#include <hip/hip_runtime.h>

#define L_T 512
#define BATCH 1024
#define LB (L_T*BATCH)
#define NT (LB/64)

typedef short bf16x8 __attribute__((ext_vector_type(8)));
typedef float f32x4 __attribute__((ext_vector_type(4)));
typedef unsigned short u16;

#define MFMA_B16(a,b,c) __builtin_amdgcn_mfma_f32_16x16x32_bf16((a),(b),(c),0,0,0)

__device__ __forceinline__ short f2bs(float f){
  union{float f; unsigned u;} c; c.f=f;
  unsigned r = (c.u + 0x7FFFu + ((c.u>>16)&1u)) >> 16;
  return (short)r;
}

__device__ __forceinline__ unsigned cvtpk(float lo, float hi){
  unsigned d;
  asm("v_cvt_pk_bf16_f32 %0, %1, %2" : "=v"(d) : "v"(lo), "v"(hi));
  return d;
}

// fast activations (validated R7-R12: absmax unchanged at 0.03125)
__device__ __forceinline__ float fsig(float x){
  return __builtin_amdgcn_rcpf(1.0f + __expf(-x));
}
__device__ __forceinline__ float ftanh(float x){
  return 1.0f - 2.0f*__builtin_amdgcn_rcpf(1.0f + __expf(2.0f*x));
}

__device__ __forceinline__ void store8(u16* d, float4 a, float4 b){
  bf16x8 v;
  v[0]=f2bs(a.x); v[1]=f2bs(a.y); v[2]=f2bs(a.z); v[3]=f2bs(a.w);
  v[4]=f2bs(b.x); v[5]=f2bs(b.y); v[6]=f2bs(b.z); v[7]=f2bs(b.w);
  *(bf16x8*)d = v;
}

__device__ __forceinline__ bf16x8 bfrag_f32(const float* p){
  float4 a = *(const float4*)p;
  float4 b = *(const float4*)(p+4);
  bf16x8 v;
  v[0]=f2bs(a.x); v[1]=f2bs(a.y); v[2]=f2bs(a.z); v[3]=f2bs(a.w);
  v[4]=f2bs(b.x); v[5]=f2bs(b.y); v[6]=f2bs(b.z); v[7]=f2bs(b.w);
  return v;
}

__device__ __forceinline__ void dma16(const void* g, void* l){
  __builtin_amdgcn_global_load_lds(
      (const __attribute__((address_space(1))) void*)g,
      (__attribute__((address_space(3))) void*)l, 16, 0, 0);
}

// ---------------------------------------------------------------------------
// K1: two-layer preprocess. x-branch: bf16 park + f32 out; u-branch: bf16
// into gen_in cols 64..127.
// ---------------------------------------------------------------------------
__device__ __forceinline__ void pre_body(
    int bid,
    const float* __restrict__ src, const float* __restrict__ W1,
    const float* __restrict__ b1, const float* __restrict__ W2,
    const float* __restrict__ b2,
    u16* __restrict__ out_b16, int ostride, int ooff,
    float* __restrict__ out_f32)
{
  __shared__ u16 in_t[64*40];
  __shared__ u16 w1t[64*40];
  __shared__ u16 w2t[64*88];
  __shared__ u16 t1t[64*88];
  __shared__ float lb1[64], lb2[64];

  const int t = threadIdx.x;
  const size_t row0 = (size_t)bid * 64;

  {
    int r = t>>2, q = t&3;
    const float* ps = src + (row0 + r)*32 + q*8;
    store8(in_t + r*40 + q*8, *(const float4*)ps, *(const float4*)(ps+4));
    const float* pw = W1 + r*32 + q*8;
    store8(w1t + r*40 + q*8, *(const float4*)pw, *(const float4*)(pw+4));
    const float* pw2 = W2 + r*64 + q*16;
    store8(w2t + r*88 + q*16,     *(const float4*)pw2,     *(const float4*)(pw2+4));
    store8(w2t + r*88 + q*16 + 8, *(const float4*)(pw2+8), *(const float4*)(pw2+12));
    if (t < 64) lb1[t] = b1[t];
    else if (t < 128) lb2[t-64] = b2[t-64];
  }
  __syncthreads();

  const int lane = t & 63, wave = t >> 6;
  const int l15 = lane & 15, l4 = lane >> 4;
  const int rs = wave*16;

  {
    bf16x8 a = *(const bf16x8*)(in_t + (rs + l15)*40 + l4*8);
    #pragma unroll
    for (int ct = 0; ct < 4; ++ct) {
      f32x4 acc = {0.f,0.f,0.f,0.f};
      bf16x8 bw = *(const bf16x8*)(w1t + (ct*16 + l15)*40 + l4*8);
      acc = MFMA_B16(a, bw, acc);
      float bias = lb1[ct*16 + l15];
      #pragma unroll
      for (int i = 0; i < 4; ++i) {
        float v = fmaxf(acc[i] + bias, 0.f);
        t1t[(rs + l4*4 + i)*88 + ct*16 + l15] = (u16)f2bs(v);
      }
    }
  }
  __syncthreads();

  {
    bf16x8 a0 = *(const bf16x8*)(t1t + (rs + l15)*88 + l4*8);
    bf16x8 a1 = *(const bf16x8*)(t1t + (rs + l15)*88 + 32 + l4*8);
    #pragma unroll
    for (int ct = 0; ct < 4; ++ct) {
      f32x4 acc = {0.f,0.f,0.f,0.f};
      bf16x8 b0 = *(const bf16x8*)(w2t + (ct*16 + l15)*88 + l4*8);
      bf16x8 b1v = *(const bf16x8*)(w2t + (ct*16 + l15)*88 + 32 + l4*8);
      acc = MFMA_B16(a0, b0, acc);
      acc = MFMA_B16(a1, b1v, acc);
      float bias = lb2[ct*16 + l15];
      #pragma unroll
      for (int i = 0; i < 4; ++i) {
        float v = fmaxf(acc[i] + bias, 0.f);
        size_t gr = row0 + rs + l4*4 + i;
        int col = ct*16 + l15;
        if (out_b16) out_b16[gr*(size_t)ostride + ooff + col] = (u16)f2bs(v);
        if (out_f32) out_f32[gr*64 + col] = v;
      }
    }
  }
}

__global__ __launch_bounds__(256) void k_pre2(
    const float* __restrict__ obs,
    const float* __restrict__ pxW1, const float* __restrict__ pxb1,
    const float* __restrict__ pxW2, const float* __restrict__ pxb2,
    u16* __restrict__ xemb16, float* __restrict__ xembf32,
    const float* __restrict__ ext,
    const float* __restrict__ puW1, const float* __restrict__ pub1,
    const float* __restrict__ puW2, const float* __restrict__ pub2,
    u16* __restrict__ gen_in)
{
  int bid = blockIdx.x;
  if (bid < NT) pre_body(bid, obs, pxW1, pxb1, pxW2, pxb2, xemb16, 64, 0, xembf32);
  else          pre_body(bid - NT, ext, puW1, pub1, puW2, pub2, gen_in, 128, 64, nullptr);
}

// ===========================================================================
// Phase kernel: 256 blocks. blocks 0-63 = INF chunk P (P<8), 64-127 = GEN
// chunk P-2 (P>=2), 128-255 = MID chunk P-1 (1<=P<=8). Chunk = 64 steps.
// Cross-phase state via global scratch; kernel boundaries give sync+coherence.
// ===========================================================================

#define SMEM_U16 39552
// mid carving (u16 offsets)
#define M_DT   0
#define M_W1T  5632
#define M_W2T  11264
#define M_TT   16896
#define M_ZW2T 22528
#define M_ZW1T 28160
#define M_ST   30720
#define M_WMUT 33280
#define M_WLST 36096
#define M_BIAS 38912   // 320 f32

// ---------------- INF role ----------------
__device__ void inf_phase(
    int P, u16* smem,
    const u16* __restrict__ xin,              // xemb16 [LB][64]
    const float* __restrict__ Wih, const float* __restrict__ Whh,
    const float* __restrict__ bih, const float* __restrict__ bhh,
    u16* __restrict__ dseq_out,               // mu region u16 view [LB][64]
    float* __restrict__ hstate)               // [1024][64] f32
{
  u16* xchunk = smem;            // 2 * 8192
  u16* ht     = smem + 16384;    // 2 * 1152

  const int t = threadIdx.x;
  const int lane = t & 63, wave = t >> 6;
  const int l15 = lane & 15, l4 = lane >> 4;
  const int b0 = blockIdx.x * 16;
  const int kcol = wave*16 + l15;
  const int c0   = wave*16 + l4*4;

  bf16x8 wihf[3][2], whhf[3][2];
  #pragma unroll
  for (int g = 0; g < 3; ++g) {
    int grow = g*64 + kcol;
    #pragma unroll
    for (int kc = 0; kc < 2; ++kc) {
      wihf[g][kc] = bfrag_f32(Wih + (size_t)grow*64 + kc*32 + l4*8);
      whhf[g][kc] = bfrag_f32(Whh + (size_t)grow*64 + kc*32 + l4*8);
    }
  }
  f32x4 bv0, bv1, bvi, bvh;
  #pragma unroll
  for (int i = 0; i < 4; ++i) {
    bv0[i] = bih[c0+i]      + bhh[c0+i];
    bv1[i] = bih[64+c0+i]   + bhh[64+c0+i];
    bvi[i] = bih[128+c0+i];
    bvh[i] = bhh[128+c0+i];
  }

  auto issue_chunk = [&](int gc, int bufi){
    const size_t step0 = (size_t)gc*8;
    u16* dst0 = xchunk + bufi*8192;
    #pragma unroll
    for (int j = 0; j < 4; ++j) {
      int o = (j*4 + wave)*1024;
      int slot = o/16 + lane;
      int r_all = slot >> 3;
      int q = slot & 7;
      int slice = r_all >> 4, r = r_all & 15;
      int qs = q ^ (r & 7);
      const u16* g = xin + ((step0 + slice)*BATCH + b0 + r)*64 + qs*8;
      dma16(g, dst0 + o/2);
    }
  };

  float h[4];
  if (P == 0) { h[0]=h[1]=h[2]=h[3]=0.f; }
  else {
    float4 hv = *(const float4*)(hstate + (size_t)(b0 + l15)*64 + c0);
    h[0]=hv.x; h[1]=hv.y; h[2]=hv.z; h[3]=hv.w;
  }

  f32x4 gp0, gp1, gp2;
  issue_chunk(P*8, 0);

  for (int cc = 0; cc < 8; ++cc) {
    const int gc = P*8 + cc;
    const int cb = cc & 1;
    const u16* xbuf = xchunk + cb*8192;
    #pragma unroll
    for (int sp = 0; sp < 8; ++sp) {
      const int step = gc*8 + sp;

      {
        uint2 pv; pv.x = cvtpk(h[0], h[1]); pv.y = cvtpk(h[2], h[3]);
        *(uint2*)(ht + (sp&1)*1152 + l15*72 + c0) = pv;
      }

      if (sp == 0) asm volatile("s_waitcnt vmcnt(0)" ::: "memory");
      asm volatile("s_waitcnt lgkmcnt(0)\n\ts_barrier" ::: "memory");

      const u16* htr = ht + (sp&1)*1152 + l15*72;
      bf16x8 ha0 = *(const bf16x8*)(htr + l4*8);
      bf16x8 ha1 = *(const bf16x8*)(htr + 32 + l4*8);

      f32x4 a0, a1, a2;
      if (sp == 0) {
        const u16* xb = xbuf + l15*64;
        bf16x8 xa[2];
        #pragma unroll
        for (int kc = 0; kc < 2; ++kc)
          xa[kc] = *(const bf16x8*)(xb + (((l4 + 4*kc) ^ (l15 & 7)) * 8));
        a0 = bv0; a1 = bv1; a2 = bvi;
        #pragma unroll
        for (int kc = 0; kc < 2; ++kc) {
          a0 = MFMA_B16(wihf[0][kc], xa[kc], a0);
          a1 = MFMA_B16(wihf[1][kc], xa[kc], a1);
          a2 = MFMA_B16(wihf[2][kc], xa[kc], a2);
        }
      } else {
        a0 = gp0; a1 = gp1; a2 = gp2;
      }

      if (sp == 1 && cc + 1 < 8) issue_chunk(gc + 1, cb ^ 1);

      f32x4 g0 = MFMA_B16(whhf[0][0], ha0, a0);
      g0       = MFMA_B16(whhf[0][1], ha1, g0);
      f32x4 g1 = MFMA_B16(whhf[1][0], ha0, a1);
      g1       = MFMA_B16(whhf[1][1], ha1, g1);
      f32x4 gn = MFMA_B16(whhf[2][0], ha0, bvh);
      gn       = MFMA_B16(whhf[2][1], ha1, gn);

      if (sp < 7) {
        const u16* xb = xbuf + (sp+1)*1024 + l15*64;
        bf16x8 xn[2];
        #pragma unroll
        for (int kc = 0; kc < 2; ++kc)
          xn[kc] = *(const bf16x8*)(xb + (((l4 + 4*kc) ^ (l15 & 7)) * 8));
        gp0 = bv0; gp1 = bv1; gp2 = bvi;
        #pragma unroll
        for (int kc = 0; kc < 2; ++kc) {
          gp0 = MFMA_B16(wihf[0][kc], xn[kc], gp0);
          gp1 = MFMA_B16(wihf[1][kc], xn[kc], gp1);
          gp2 = MFMA_B16(wihf[2][kc], xn[kc], gp2);
        }
      }

      #pragma unroll
      for (int i = 0; i < 4; ++i) {
        float r = fsig(g0[i]);
        float z = fsig(g1[i]);
        float n = ftanh(a2[i] + r*gn[i]);
        h[i] = z*(h[i] - n) + n;
      }

      {
        uint2 dv; dv.x = cvtpk(h[0], h[1]); dv.y = cvtpk(h[2], h[3]);
        *(uint2*)(dseq_out + ((size_t)step*BATCH + b0 + l15)*64 + c0) = dv;
      }
    }
  }

  float4 hv; hv.x=h[0]; hv.y=h[1]; hv.z=h[2]; hv.w=h[3];
  *(float4*)(hstate + (size_t)(b0 + l15)*64 + c0) = hv;
}

// ---------------- GEN role ----------------
__device__ void gen_phase(
    int P, u16* smem,
    const u16* __restrict__ xin,              // gen_in [LB][128]
    const float* __restrict__ Wih, const float* __restrict__ Whh,
    const float* __restrict__ bih, const float* __restrict__ bhh,
    float* __restrict__ hseq,
    float* __restrict__ hstate)               // hn region [1024][64] f32
{
  u16* xchunk = smem;            // 2 * 16384
  u16* ht     = smem + 32768;    // 2 * 1152

  const int t = threadIdx.x;
  const int lane = t & 63, wave = t >> 6;
  const int l15 = lane & 15, l4 = lane >> 4;
  const int b0 = (blockIdx.x - 64) * 16;
  const int kcol = wave*16 + l15;
  const int c0   = wave*16 + l4*4;

  bf16x8 wihf[3][4], whhf[3][2];
  #pragma unroll
  for (int g = 0; g < 3; ++g) {
    int grow = g*64 + kcol;
    #pragma unroll
    for (int kc = 0; kc < 4; ++kc)
      wihf[g][kc] = bfrag_f32(Wih + (size_t)grow*128 + kc*32 + l4*8);
    #pragma unroll
    for (int kc = 0; kc < 2; ++kc)
      whhf[g][kc] = bfrag_f32(Whh + (size_t)grow*64 + kc*32 + l4*8);
  }
  f32x4 bv0, bv1, bvi, bvh;
  #pragma unroll
  for (int i = 0; i < 4; ++i) {
    bv0[i] = bih[c0+i]      + bhh[c0+i];
    bv1[i] = bih[64+c0+i]   + bhh[64+c0+i];
    bvi[i] = bih[128+c0+i];
    bvh[i] = bhh[128+c0+i];
  }

  auto issue_chunk = [&](int gc, int bufi){
    const size_t step0 = (size_t)gc*8;
    u16* dst0 = xchunk + bufi*16384;
    #pragma unroll
    for (int j = 0; j < 8; ++j) {
      int o = (j*4 + wave)*1024;
      int slot = o/16 + lane;
      int r_all = slot >> 4;
      int q = slot & 15;
      int slice = r_all >> 4, r = r_all & 15;
      int qs = q ^ (r & 7);
      const u16* g = xin + ((step0 + slice)*BATCH + b0 + r)*128 + qs*8;
      dma16(g, dst0 + o/2);
    }
  };

  float h[4];
  if (P == 2) { h[0]=h[1]=h[2]=h[3]=0.f; }
  else {
    float4 hv = *(const float4*)(hstate + (size_t)(b0 + l15)*64 + c0);
    h[0]=hv.x; h[1]=hv.y; h[2]=hv.z; h[3]=hv.w;
  }

  const int C0 = (P - 2) * 8;
  f32x4 gp0, gp1, gp2;
  issue_chunk(C0, 0);

  for (int cc = 0; cc < 8; ++cc) {
    const int gc = C0 + cc;
    const int cb = cc & 1;
    const u16* xbuf = xchunk + cb*16384;
    #pragma unroll
    for (int sp = 0; sp < 8; ++sp) {
      const int step = gc*8 + sp;

      {
        uint2 pv; pv.x = cvtpk(h[0], h[1]); pv.y = cvtpk(h[2], h[3]);
        *(uint2*)(ht + (sp&1)*1152 + l15*72 + c0) = pv;
        float4 hv; hv.x=h[0]; hv.y=h[1]; hv.z=h[2]; hv.w=h[3];
        *(float4*)(hseq + ((size_t)step*BATCH + b0 + l15)*64 + c0) = hv;
      }

      if (sp == 0) asm volatile("s_waitcnt vmcnt(0)" ::: "memory");
      asm volatile("s_waitcnt lgkmcnt(0)\n\ts_barrier" ::: "memory");

      const u16* htr = ht + (sp&1)*1152 + l15*72;
      bf16x8 ha0 = *(const bf16x8*)(htr + l4*8);
      bf16x8 ha1 = *(const bf16x8*)(htr + 32 + l4*8);

      f32x4 a0, a1, a2;
      if (sp == 0) {
        const u16* xb = xbuf + l15*128;
        bf16x8 xa[4];
        #pragma unroll
        for (int kc = 0; kc < 4; ++kc)
          xa[kc] = *(const bf16x8*)(xb + (((l4 + 4*kc) ^ (l15 & 7)) * 8));
        a0 = bv0; a1 = bv1; a2 = bvi;
        #pragma unroll
        for (int kc = 0; kc < 4; ++kc) {
          a0 = MFMA_B16(wihf[0][kc], xa[kc], a0);
          a1 = MFMA_B16(wihf[1][kc], xa[kc], a1);
          a2 = MFMA_B16(wihf[2][kc], xa[kc], a2);
        }
      } else {
        a0 = gp0; a1 = gp1; a2 = gp2;
      }

      if (sp == 1 && cc + 1 < 8) issue_chunk(gc + 1, cb ^ 1);

      f32x4 g0 = MFMA_B16(whhf[0][0], ha0, a0);
      g0       = MFMA_B16(whhf[0][1], ha1, g0);
      f32x4 g1 = MFMA_B16(whhf[1][0], ha0, a1);
      g1       = MFMA_B16(whhf[1][1], ha1, g1);
      f32x4 gn = MFMA_B16(whhf[2][0], ha0, bvh);
      gn       = MFMA_B16(whhf[2][1], ha1, gn);

      if (sp < 7) {
        const u16* xb = xbuf + (sp+1)*2048 + l15*128;
        bf16x8 xn[4];
        #pragma unroll
        for (int kc = 0; kc < 4; ++kc)
          xn[kc] = *(const bf16x8*)(xb + (((l4 + 4*kc) ^ (l15 & 7)) * 8));
        gp0 = bv0; gp1 = bv1; gp2 = bvi;
        #pragma unroll
        for (int kc = 0; kc < 4; ++kc) {
          gp0 = MFMA_B16(wihf[0][kc], xn[kc], gp0);
          gp1 = MFMA_B16(wihf[1][kc], xn[kc], gp1);
          gp2 = MFMA_B16(wihf[2][kc], xn[kc], gp2);
        }
      }

      #pragma unroll
      for (int i = 0; i < 4; ++i) {
        float r = fsig(g0[i]);
        float z = fsig(g1[i]);
        float n = ftanh(a2[i] + r*gn[i]);
        h[i] = z*(h[i] - n) + n;
      }
    }
  }

  float4 hv; hv.x=h[0]; hv.y=h[1]; hv.z=h[2]; hv.w=h[3];
  *(float4*)(hstate + (size_t)(b0 + l15)*64 + c0) = hv;
}

// ---------------- MID role ----------------
__device__ void mid_phase(
    int P, u16* smem,
    const u16* __restrict__ dseq,             // mu region u16 view [LB][64]
    const float* __restrict__ eps,
    const float* __restrict__ W1, const float* __restrict__ b1,
    const float* __restrict__ W2, const float* __restrict__ b2,
    const float* __restrict__ Wmu, const float* __restrict__ bmu,
    const float* __restrict__ Wls, const float* __restrict__ bls,
    const float* __restrict__ zW1, const float* __restrict__ zb1,
    const float* __restrict__ zW2, const float* __restrict__ zb2,
    float* __restrict__ out_mu, float* __restrict__ out_ls, float* __restrict__ out_s,
    u16* __restrict__ gen_in)
{
  u16* dt   = smem + M_DT;
  u16* w1t  = smem + M_W1T;
  u16* w2t  = smem + M_W2T;
  u16* tt   = smem + M_TT;
  u16* zw2t = smem + M_ZW2T;
  u16* zw1t = smem + M_ZW1T;
  u16* st   = smem + M_ST;
  u16* wmut = smem + M_WMUT;
  u16* wlst = smem + M_WLST;
  float* fb = (float*)(smem + M_BIAS);
  float* lb1 = fb, *lb2 = fb+64, *lbz1 = fb+128, *lbz2 = fb+192;
  float* lbmu = fb+256, *lbls = fb+288;

  const int t = threadIdx.x;

  // weights + biases once per phase
  {
    int r = t>>2, q = t&3;
    const float* p1 = W1 + r*64 + q*16;
    store8(w1t + r*88 + q*16,     *(const float4*)p1,     *(const float4*)(p1+4));
    store8(w1t + r*88 + q*16 + 8, *(const float4*)(p1+8), *(const float4*)(p1+12));
    const float* p2 = W2 + r*64 + q*16;
    store8(w2t + r*88 + q*16,     *(const float4*)p2,     *(const float4*)(p2+4));
    store8(w2t + r*88 + q*16 + 8, *(const float4*)(p2+8), *(const float4*)(p2+12));
    const float* pz2 = zW2 + r*64 + q*16;
    store8(zw2t + r*88 + q*16,     *(const float4*)pz2,     *(const float4*)(pz2+4));
    store8(zw2t + r*88 + q*16 + 8, *(const float4*)(pz2+8), *(const float4*)(pz2+12));
    const float* pz1 = zW1 + r*32 + q*8;
    store8(zw1t + r*40 + q*8, *(const float4*)pz1, *(const float4*)(pz1+4));
    if (t < 128) {
      int r2 = t>>2, q2 = t&3;
      const float* pm = Wmu + r2*64 + q2*16;
      store8(wmut + r2*88 + q2*16,     *(const float4*)pm,     *(const float4*)(pm+4));
      store8(wmut + r2*88 + q2*16 + 8, *(const float4*)(pm+8), *(const float4*)(pm+12));
    } else {
      int t2 = t - 128; int r2 = t2>>2, q2 = t2&3;
      const float* pl = Wls + r2*64 + q2*16;
      store8(wlst + r2*88 + q2*16,     *(const float4*)pl,     *(const float4*)(pl+4));
      store8(wlst + r2*88 + q2*16 + 8, *(const float4*)(pl+8), *(const float4*)(pl+12));
    }
    if (t < 64) { lb1[t] = b1[t]; lbz1[t] = zb1[t]; }
    else if (t < 128) { lb2[t-64] = b2[t-64]; lbz2[t-64] = zb2[t-64]; }
    else if (t < 160) lbmu[t-128] = bmu[t-128];
    else if (t < 192) lbls[t-160] = bls[t-160];
  }

  const int lane = t & 63, wave = t >> 6;
  const int l15 = lane & 15, l4 = lane >> 4;
  const int rs = wave*16;
  const int bidm = blockIdx.x - 128;          // 0..127
  const size_t t0 = (size_t)(P - 1) * 64;

  for (int j = 0; j < 8; ++j) {
    const size_t row0 = t0*BATCH + ((size_t)bidm*8 + j)*64;

    __syncthreads();  // weights ready (j==0) / WAR vs prev iteration reads
    {
      int r = t>>2, q = t&3;
      const u16* pd = dseq + (row0 + r)*64 + q*16;
      *(bf16x8*)(dt + r*88 + q*16)     = *(const bf16x8*)pd;
      *(bf16x8*)(dt + r*88 + q*16 + 8) = *(const bf16x8*)(pd + 8);
    }
    __syncthreads();

    // gated hidden
    {
      bf16x8 a0 = *(const bf16x8*)(dt + (rs + l15)*88 + l4*8);
      bf16x8 a1 = *(const bf16x8*)(dt + (rs + l15)*88 + 32 + l4*8);
      #pragma unroll
      for (int ct = 0; ct < 4; ++ct) {
        f32x4 c1 = {0.f,0.f,0.f,0.f}, c2 = {0.f,0.f,0.f,0.f};
        bf16x8 w1a = *(const bf16x8*)(w1t + (ct*16 + l15)*88 + l4*8);
        bf16x8 w1b = *(const bf16x8*)(w1t + (ct*16 + l15)*88 + 32 + l4*8);
        bf16x8 w2a = *(const bf16x8*)(w2t + (ct*16 + l15)*88 + l4*8);
        bf16x8 w2b = *(const bf16x8*)(w2t + (ct*16 + l15)*88 + 32 + l4*8);
        c1 = MFMA_B16(a0, w1a, c1); c1 = MFMA_B16(a1, w1b, c1);
        c2 = MFMA_B16(a0, w2a, c2); c2 = MFMA_B16(a1, w2b, c2);
        float bb1 = lb1[ct*16 + l15], bb2 = lb2[ct*16 + l15];
        #pragma unroll
        for (int i = 0; i < 4; ++i) {
          float tv = fmaxf(c1[i] + bb1, 0.f) * fsig(c2[i] + bb2);
          tt[(rs + l4*4 + i)*88 + ct*16 + l15] = (u16)f2bs(tv);
        }
      }
    }
    __syncthreads();

    // heads + sample
    {
      bf16x8 a0 = *(const bf16x8*)(tt + (rs + l15)*88 + l4*8);
      bf16x8 a1 = *(const bf16x8*)(tt + (rs + l15)*88 + 32 + l4*8);
      #pragma unroll
      for (int ct = 0; ct < 2; ++ct) {
        f32x4 cmu = {0.f,0.f,0.f,0.f}, cls = {0.f,0.f,0.f,0.f};
        bf16x8 wma = *(const bf16x8*)(wmut + (ct*16 + l15)*88 + l4*8);
        bf16x8 wmb = *(const bf16x8*)(wmut + (ct*16 + l15)*88 + 32 + l4*8);
        bf16x8 wla = *(const bf16x8*)(wlst + (ct*16 + l15)*88 + l4*8);
        bf16x8 wlb = *(const bf16x8*)(wlst + (ct*16 + l15)*88 + 32 + l4*8);
        cmu = MFMA_B16(a0, wma, cmu); cmu = MFMA_B16(a1, wmb, cmu);
        cls = MFMA_B16(a0, wla, cls); cls = MFMA_B16(a1, wlb, cls);
        float bm = lbmu[ct*16 + l15], bl = lbls[ct*16 + l15];
        #pragma unroll
        for (int i = 0; i < 4; ++i) {
          size_t R = row0 + rs + l4*4 + i;
          int col = ct*16 + l15;
          float mu = cmu[i] + bm;
          float ls = cls[i] + bl;
          float e  = eps[R*32 + col];
          float s  = mu + __expf(0.5f*ls)*e;
          out_mu[R*32 + col] = mu;
          out_ls[R*32 + col] = ls;
          out_s [R*32 + col] = s;
          st[(rs + l4*4 + i)*40 + col] = (u16)f2bs(s);
        }
      }
    }
    __syncthreads();

    // z_emb layer 1 -> dt
    {
      bf16x8 a = *(const bf16x8*)(st + (rs + l15)*40 + l4*8);
      #pragma unroll
      for (int ct = 0; ct < 4; ++ct) {
        f32x4 acc = {0.f,0.f,0.f,0.f};
        bf16x8 bw = *(const bf16x8*)(zw1t + (ct*16 + l15)*40 + l4*8);
        acc = MFMA_B16(a, bw, acc);
        float bias = lbz1[ct*16 + l15];
        #pragma unroll
        for (int i = 0; i < 4; ++i) {
          float v = fmaxf(acc[i] + bias, 0.f);
          dt[(rs + l4*4 + i)*88 + ct*16 + l15] = (u16)f2bs(v);
        }
      }
    }
    __syncthreads();

    // z_emb layer 2 -> gen_in cols 0..63
    {
      bf16x8 a0 = *(const bf16x8*)(dt + (rs + l15)*88 + l4*8);
      bf16x8 a1 = *(const bf16x8*)(dt + (rs + l15)*88 + 32 + l4*8);
      #pragma unroll
      for (int ct = 0; ct < 4; ++ct) {
        f32x4 acc = {0.f,0.f,0.f,0.f};
        bf16x8 b0 = *(const bf16x8*)(zw2t + (ct*16 + l15)*88 + l4*8);
        bf16x8 b1v = *(const bf16x8*)(zw2t + (ct*16 + l15)*88 + 32 + l4*8);
        acc = MFMA_B16(a0, b0, acc);
        acc = MFMA_B16(a1, b1v, acc);
        float bias = lbz2[ct*16 + l15];
        #pragma unroll
        for (int i = 0; i < 4; ++i) {
          float v = fmaxf(acc[i] + bias, 0.f);
          size_t gr = row0 + rs + l4*4 + i;
          gen_in[gr*128 + ct*16 + l15] = (u16)f2bs(v);
        }
      }
    }
  }
}

// ---------------- dispatcher ----------------
__global__ __launch_bounds__(256, 1) void k_phase(
    int P,
    const u16* xemb16, u16* gen_in,
    const float* eps,
    const float* iWih, const float* iWhh, const float* ibih, const float* ibhh,
    const float* gWih, const float* gWhh, const float* gbih, const float* gbhh,
    const float* poW1, const float* pob1, const float* poW2, const float* pob2,
    const float* poWmu, const float* pobmu, const float* poWls, const float* pobls,
    const float* pzW1, const float* pzb1, const float* pzW2, const float* pzb2,
    u16* dseq, float* out_mu, float* out_ls, float* out_s,
    float* hseq, float* hn, float* hstate_inf)
{
  __shared__ u16 smem[SMEM_U16];
  const int bid = blockIdx.x;
  if (bid < 64) {
    if (P < 8)
      inf_phase(P, smem, xemb16, iWih, iWhh, ibih, ibhh, dseq, hstate_inf);
  } else if (bid < 128) {
    if (P >= 2)
      gen_phase(P, smem, gen_in, gWih, gWhh, gbih, gbhh, hseq, hn);
  } else {
    if (P >= 1 && P <= 8)
      mid_phase(P, smem, dseq, eps, poW1, pob1, poW2, pob2,
                poWmu, pobmu, poWls, pobls, pzW1, pzb1, pzW2, pzb2,
                out_mu, out_ls, out_s, gen_in);
  }
}

// ---------------------------------------------------------------------------

extern "C" void kernel_launch(void* const* d_in, const int* in_sizes, int n_in,
                              void* d_out, int out_size, void* d_ws, size_t ws_size,
                              hipStream_t stream) {
  const float* ext  = (const float*)d_in[0];
  const float* obs  = (const float*)d_in[1];
  const float* eps  = (const float*)d_in[2];
  const float* puW1 = (const float*)d_in[3];  const float* pub1 = (const float*)d_in[4];
  const float* puW2 = (const float*)d_in[5];  const float* pub2 = (const float*)d_in[6];
  const float* pxW1 = (const float*)d_in[7];  const float* pxb1 = (const float*)d_in[8];
  const float* pxW2 = (const float*)d_in[9];  const float* pxb2 = (const float*)d_in[10];
  const float* pzW1 = (const float*)d_in[11]; const float* pzb1 = (const float*)d_in[12];
  const float* pzW2 = (const float*)d_in[13]; const float* pzb2 = (const float*)d_in[14];
  const float* poW1 = (const float*)d_in[15]; const float* pob1 = (const float*)d_in[16];
  const float* poW2 = (const float*)d_in[17]; const float* pob2 = (const float*)d_in[18];
  const float* poWmu= (const float*)d_in[19]; const float* pobmu= (const float*)d_in[20];
  const float* poWls= (const float*)d_in[21]; const float* pobls= (const float*)d_in[22];
  const float* iWih = (const float*)d_in[23]; const float* iWhh = (const float*)d_in[24];
  const float* ibih = (const float*)d_in[25]; const float* ibhh = (const float*)d_in[26];
  const float* gWih = (const float*)d_in[27]; const float* gWhh = (const float*)d_in[28];
  const float* gbih = (const float*)d_in[29]; const float* gbhh = (const float*)d_in[30];

  float* out = (float*)d_out;
  const size_t OFF_MU   = 0;
  const size_t OFF_LS   = (size_t)LB*32;
  const size_t OFF_S    = (size_t)LB*64;
  const size_t OFF_HSEQ = (size_t)LB*96;
  const size_t OFF_XEMB = (size_t)LB*96 + (size_t)LB*64;
  const size_t OFF_HN   = OFF_XEMB + (size_t)LB*64;

  u16* gen_in = (u16*)d_ws;                              // [LB][128] bf16 (z|u)
  u16* dseq   = (u16*)(out + OFF_MU);                    // [LB][64] bf16 park (mu region)
  u16* xemb16 = (u16*)(out + OFF_HSEQ + (size_t)LB*32);  // [LB][64] bf16 park (hseq 2nd half)
  float* hstate_inf = out + OFF_S + (size_t)LB*32 - 65536;  // s-region tail (steps 510-511, rewritten by mid phase 8)

  // 1. x_emb (f32 out + bf16 park) and u_emb (gen_in hi)
  k_pre2<<<2*NT, 256, 0, stream>>>(obs, pxW1, pxb1, pxW2, pxb2, xemb16, out + OFF_XEMB,
                                   ext, puW1, pub1, puW2, pub2, gen_in);
  // 2. pipelined phases: inf chunk P || mid chunk P-1 || gen chunk P-2
  for (int P = 0; P < 10; ++P) {
    k_phase<<<256, 256, 0, stream>>>(P, xemb16, gen_in, eps,
                                     iWih, iWhh, ibih, ibhh,
                                     gWih, gWhh, gbih, gbhh,
                                     poW1, pob1, poW2, pob2,
                                     poWmu, pobmu, poWls, pobls,
                                     pzW1, pzb1, pzW2, pzb2,
                                     dseq, out + OFF_MU, out + OFF_LS, out + OFF_S,
                                     out + OFF_HSEQ, out + OFF_HN, hstate_inf);
  }
}